// Round 1
// baseline (43.845 us; speedup 1.0000x reference)
//
#include <hip/hip_runtime.h>

typedef float f4 __attribute__((ext_vector_type(4)));

#define N_ROWS 8192                    // 8 * 32 * 32
#define POOLED_PER_INPUT (N_ROWS * 64) // 524288 floats
#define GRAM_BLOCKS 128
#define ROWS_PER_BLK 64
#define LDS_PAD 68                     // keeps 16B alignment, spreads banks

// ws float layout:
// [0, 524288)              A pooled, column-major: [c][row] -> c*8192 + row
// [524288, 1048576)        B pooled, same layout
// [1048576, 1048576+128*12288) per-block Gram partials [blk][3][4096]
// [next 16]                reduce-kernel block partials

__global__ __launch_bounds__(256) void pool_kernel(
    const float* __restrict__ p1, const float* __restrict__ p2,
    float* __restrict__ pooled)
{
    unsigned g  = blockIdx.x * 256u + threadIdx.x;   // 0 .. 2*8*64*32*32-1
    unsigned oj = g & 31u;
    unsigned oi = (g >> 5) & 31u;
    unsigned c  = (g >> 10) & 63u;
    unsigned b  = (g >> 16) & 7u;
    unsigned in = g >> 19;
    const float* src = (in ? p2 : p1)
                     + (((b * 64u + c) * 128u + oi * 4u) * 128u + oj * 4u);
    f4 s0 = *(const f4*)(src);
    f4 s1 = *(const f4*)(src + 128);
    f4 s2 = *(const f4*)(src + 256);
    f4 s3 = *(const f4*)(src + 384);
    f4 s = s0 + s1 + s2 + s3;
    float sum = (s[0] + s[1]) + (s[2] + s[3]);
    unsigned row = b * 1024u + oi * 32u + oj;
    pooled[in * POOLED_PER_INPUT + c * 8192u + row] = sum * 0.0625f;
}

__global__ __launch_bounds__(256) void gram_kernel(
    const float* __restrict__ pooled, float* __restrict__ partials)
{
    __shared__ float la[64 * LDS_PAD];
    __shared__ float lb[64 * LDS_PAD];
    __shared__ float sa[64], sb[64];
    const int t  = threadIdx.x;
    const int r0 = blockIdx.x * ROWS_PER_BLK;

    // Stage 64 rows x 64 channels of A and B, column-major (matches global).
    #pragma unroll
    for (int k = 0; k < 4; ++k) {
        int idx4 = k * 256 + t;        // 0..1023 float4s (64 c x 16 row-quads)
        int c    = idx4 >> 4;
        int rq   = (idx4 & 15) * 4;
        *(f4*)&la[c * LDS_PAD + rq] =
            *(const f4*)&pooled[c * 8192 + r0 + rq];
        *(f4*)&lb[c * LDS_PAD + rq] =
            *(const f4*)&pooled[POOLED_PER_INPUT + c * 8192 + r0 + rq];
    }
    __syncthreads();

    // Row L2 norms -> reciprocal scale (matches ref: 1/max(sqrt(ss), 1e-8)).
    if (t < 64) {
        float ss = 0.f;
        for (int c = 0; c < 64; ++c) { float v = la[c * LDS_PAD + t]; ss += v * v; }
        sa[t] = 1.0f / fmaxf(sqrtf(ss), 1e-8f);
    } else if (t < 128) {
        int r = t - 64;
        float ss = 0.f;
        for (int c = 0; c < 64; ++c) { float v = lb[c * LDS_PAD + r]; ss += v * v; }
        sb[r] = 1.0f / fmaxf(sqrtf(ss), 1e-8f);
    }
    __syncthreads();

    // Rescale rows in place.
    #pragma unroll
    for (int k = 0; k < 16; ++k) {
        int idx = k * 256 + t;         // 0..4095
        int c = idx >> 6, r = idx & 63;
        la[c * LDS_PAD + r] *= sa[r];
        lb[c * LDS_PAD + r] *= sb[r];
    }
    __syncthreads();

    // Each thread owns a 4x4 tile of each 64x64 Gram: rows c1.., cols c2..
    const int c1 = (t >> 4) * 4;
    const int c2 = (t & 15) * 4;
    f4 aa[4] = {}; f4 ab[4] = {}; f4 bb[4] = {};

    for (int rq = 0; rq < ROWS_PER_BLK; rq += 4) {
        f4 a1[4], a2[4], b1[4], b2[4];
        #pragma unroll
        for (int i = 0; i < 4; ++i) {
            a1[i] = *(const f4*)&la[(c1 + i) * LDS_PAD + rq];
            a2[i] = *(const f4*)&la[(c2 + i) * LDS_PAD + rq];
            b1[i] = *(const f4*)&lb[(c1 + i) * LDS_PAD + rq];
            b2[i] = *(const f4*)&lb[(c2 + i) * LDS_PAD + rq];
        }
        #pragma unroll
        for (int i = 0; i < 4; ++i)
            #pragma unroll
            for (int j = 0; j < 4; ++j)
                #pragma unroll
                for (int l = 0; l < 4; ++l) {
                    aa[i][j] = fmaf(a1[i][l], a2[j][l], aa[i][j]);
                    ab[i][j] = fmaf(a1[i][l], b2[j][l], ab[i][j]);
                    bb[i][j] = fmaf(b1[i][l], b2[j][l], bb[i][j]);
                }
    }

    float* P = partials + blockIdx.x * (3 * 4096);
    #pragma unroll
    for (int i = 0; i < 4; ++i) {
        *(f4*)&P[0 * 4096 + (c1 + i) * 64 + c2] = aa[i];
        *(f4*)&P[1 * 4096 + (c1 + i) * 64 + c2] = ab[i];
        *(f4*)&P[2 * 4096 + (c1 + i) * 64 + c2] = bb[i];
    }
}

__global__ __launch_bounds__(256) void reduce_kernel(
    const float* __restrict__ partials, float* __restrict__ out16)
{
    int e = blockIdx.x * 256 + threadIdx.x;   // Gram entry 0..4095
    float saa = 0.f, sab = 0.f, sbb = 0.f;
    for (int p = 0; p < GRAM_BLOCKS; ++p) {
        const float* P = partials + p * (3 * 4096);
        saa += P[e];
        sab += P[4096 + e];
        sbb += P[8192 + e];
    }
    float v = fmaf(saa, saa, fmaf(sbb, sbb, -2.0f * (sab * sab)));
    __shared__ float red[256];
    red[threadIdx.x] = v;
    __syncthreads();
    for (int s = 128; s > 0; s >>= 1) {
        if (threadIdx.x < s) red[threadIdx.x] += red[threadIdx.x + s];
        __syncthreads();
    }
    if (threadIdx.x == 0) out16[blockIdx.x] = red[0];
}

__global__ void final_kernel(const float* __restrict__ out16,
                             float* __restrict__ out)
{
    if (threadIdx.x == 0) {
        float s = 0.f;
        for (int i = 0; i < 16; ++i) s += out16[i];
        out[0] = s * (1.0f / (8192.0f * 8192.0f));
    }
}

extern "C" void kernel_launch(void* const* d_in, const int* in_sizes, int n_in,
                              void* d_out, int out_size, void* d_ws, size_t ws_size,
                              hipStream_t stream)
{
    const float* p1 = (const float*)d_in[0];
    const float* p2 = (const float*)d_in[1];
    float* ws       = (float*)d_ws;
    float* pooled   = ws;                                   // 2 * 524288
    float* partials = ws + 2 * POOLED_PER_INPUT;            // 128 * 12288
    float* out16    = partials + GRAM_BLOCKS * 3 * 4096;    // 16

    // total ws use: ~10.5 MB
    pool_kernel  <<<4096, 256, 0, stream>>>(p1, p2, pooled);
    gram_kernel  <<<GRAM_BLOCKS, 256, 0, stream>>>(pooled, partials);
    reduce_kernel<<<16, 256, 0, stream>>>(partials, out16);
    final_kernel <<<1, 64, 0, stream>>>(out16, (float*)d_out);
}

// Round 2
// 36.455 us; speedup vs baseline: 1.2027x; 1.2027x over previous
//
#include <hip/hip_runtime.h>

typedef float f4 __attribute__((ext_vector_type(4)));

#define PAD 68              // LDS row pitch (floats); 68%32=4 spreads banks, 16B-aligned
#define NPART 256           // gram blocks = partial count
#define PART_STRIDE 12288   // 3 * 64*64 floats per block partial

// ws layout (floats):
// [0, 3145728)      partials [256][3][4096]
// [3145728, +256)   per-block v partials (K2)
// [3145984]         uint counter

__global__ __launch_bounds__(256) void fused_gram_kernel(
    const float* __restrict__ p1, const float* __restrict__ p2,
    float* __restrict__ partials, unsigned* __restrict__ cnt)
{
    __shared__ float la[32 * PAD];
    __shared__ float lb[32 * PAD];
    __shared__ float nred[2][32][9];
    __shared__ float sa[32], sb[32];
    const int t  = threadIdx.x;
    const int b  = blockIdx.x >> 5;   // batch 0..7
    const int oi = blockIdx.x & 31;   // pooled row strip 0..31

    if (blockIdx.x == 0 && t == 0) *cnt = 0u;   // reset K2's ticket each call

    // ---- pool 4x4 means: 64 ch x 32 oj per input, straight into LDS [oj][c]
    #pragma unroll
    for (int k = 0; k < 8; ++k) {
        const int idx = k * 256 + t;
        const int c   = idx >> 5;
        const int oj  = idx & 31;
        const long off = (long)((b * 64 + c) * 128 + oi * 4) * 128 + oj * 4;
        const float* s1 = p1 + off;
        const float* s2 = p2 + off;
        f4 va = *(const f4*)(s1) + *(const f4*)(s1 + 128)
              + *(const f4*)(s1 + 256) + *(const f4*)(s1 + 384);
        f4 vb = *(const f4*)(s2) + *(const f4*)(s2 + 128)
              + *(const f4*)(s2 + 256) + *(const f4*)(s2 + 384);
        la[oj * PAD + c] = ((va[0] + va[1]) + (va[2] + va[3])) * 0.0625f;
        lb[oj * PAD + c] = ((vb[0] + vb[1]) + (vb[2] + vb[3])) * 0.0625f;
    }
    __syncthreads();

    // ---- row L2 norms (over 64 channels), 8-way split then combine
    {
        const int r = t & 31, q = t >> 5;     // q = 0..7, 8 channels each
        float ssa = 0.f, ssb = 0.f;
        #pragma unroll
        for (int j = 0; j < 8; ++j) {
            float va = la[r * PAD + q * 8 + j]; ssa = fmaf(va, va, ssa);
            float vb = lb[r * PAD + q * 8 + j]; ssb = fmaf(vb, vb, ssb);
        }
        nred[0][r][q] = ssa;
        nred[1][r][q] = ssb;
    }
    __syncthreads();
    if (t < 64) {
        const int m = t >> 5, r = t & 31;
        float ss = 0.f;
        #pragma unroll
        for (int q = 0; q < 8; ++q) ss += nred[m][r][q];
        const float rs = 1.0f / fmaxf(sqrtf(ss), 1e-8f);
        if (m) sb[r] = rs; else sa[r] = rs;
    }
    __syncthreads();

    // ---- scale rows in place
    #pragma unroll
    for (int k = 0; k < 8; ++k) {
        const int idx = k * 256 + t;
        const int c = idx >> 5, oj = idx & 31;
        la[oj * PAD + c] *= sa[oj];
        lb[oj * PAD + c] *= sb[oj];
    }
    __syncthreads();

    // ---- three 64x64 channel Grams over this block's 32 rows.
    // thread owns 4x4 tile (c1 rows, c2 cols) of each of AA, AB, BB.
    const int c1 = (t >> 4) * 4;
    const int c2 = (t & 15) * 4;
    f4 aa[4] = {}; f4 ab[4] = {}; f4 bb[4] = {};

    #pragma unroll 4
    for (int r = 0; r < 32; ++r) {
        const f4 a1 = *(const f4*)&la[r * PAD + c1];
        const f4 a2 = *(const f4*)&la[r * PAD + c2];
        const f4 b1 = *(const f4*)&lb[r * PAD + c1];
        const f4 b2 = *(const f4*)&lb[r * PAD + c2];
        #pragma unroll
        for (int i = 0; i < 4; ++i) {
            aa[i] += a2 * a1[i];
            ab[i] += b2 * a1[i];
            bb[i] += b2 * b1[i];
        }
    }

    float* P = partials + (long)blockIdx.x * PART_STRIDE;
    #pragma unroll
    for (int i = 0; i < 4; ++i) {
        *(f4*)&P[0 * 4096 + (c1 + i) * 64 + c2] = aa[i];
        *(f4*)&P[1 * 4096 + (c1 + i) * 64 + c2] = ab[i];
        *(f4*)&P[2 * 4096 + (c1 + i) * 64 + c2] = bb[i];
    }
}

// 256 blocks x 16 gram entries: sum partials over the 256 blocks, form
// v = saa^2 - 2 sab^2 + sbb^2 per entry, block-reduce, last block finishes.
__global__ __launch_bounds__(256) void reduce_kernel(
    const float* __restrict__ partials, float* __restrict__ bpart,
    unsigned* __restrict__ cnt, float* __restrict__ out)
{
    __shared__ float red[3][16][17];
    __shared__ float vred[16];
    __shared__ float fr[256];
    __shared__ unsigned last_flag;
    const int t  = threadIdx.x;
    const int el = t & 15;       // entry within block
    const int pc = t >> 4;       // partial chunk 0..15 (16 partials each)
    const int e  = blockIdx.x * 16 + el;

    float saa = 0.f, sab = 0.f, sbb = 0.f;
    #pragma unroll 4
    for (int i = 0; i < 16; ++i) {
        const float* P = partials + (long)(pc * 16 + i) * PART_STRIDE;
        saa += P[e];
        sab += P[4096 + e];
        sbb += P[8192 + e];
    }
    red[0][el][pc] = saa; red[1][el][pc] = sab; red[2][el][pc] = sbb;
    __syncthreads();

    if (t < 16) {
        float a = 0.f, m = 0.f, bv = 0.f;
        #pragma unroll
        for (int p = 0; p < 16; ++p) {
            a  += red[0][t][p];
            m  += red[1][t][p];
            bv += red[2][t][p];
        }
        vred[t] = fmaf(a, a, fmaf(bv, bv, -2.0f * (m * m)));
    }
    __syncthreads();

    if (t == 0) {
        float s = 0.f;
        #pragma unroll
        for (int i = 0; i < 16; ++i) s += vred[i];
        __hip_atomic_store(&bpart[blockIdx.x], s, __ATOMIC_RELEASE,
                           __HIP_MEMORY_SCOPE_AGENT);
        unsigned old = __hip_atomic_fetch_add(cnt, 1u, __ATOMIC_ACQ_REL,
                                              __HIP_MEMORY_SCOPE_AGENT);
        last_flag = (old == NPART - 1) ? 1u : 0u;
    }
    __syncthreads();

    if (last_flag) {   // block-uniform
        fr[t] = __hip_atomic_load(&bpart[t], __ATOMIC_ACQUIRE,
                                  __HIP_MEMORY_SCOPE_AGENT);
        __syncthreads();
        for (int s2 = 128; s2 > 0; s2 >>= 1) {
            if (t < s2) fr[t] += fr[t + s2];
            __syncthreads();
        }
        if (t == 0) out[0] = fr[0] * (1.0f / 67108864.0f);  // / 8192^2
    }
}

extern "C" void kernel_launch(void* const* d_in, const int* in_sizes, int n_in,
                              void* d_out, int out_size, void* d_ws, size_t ws_size,
                              hipStream_t stream)
{
    const float* p1 = (const float*)d_in[0];
    const float* p2 = (const float*)d_in[1];
    float* ws       = (float*)d_ws;
    float* partials = ws;                                  // 256*12288
    float* bpart    = ws + (long)NPART * PART_STRIDE;      // 256
    unsigned* cnt   = (unsigned*)(bpart + NPART);          // 1

    fused_gram_kernel<<<NPART, 256, 0, stream>>>(p1, p2, partials, cnt);
    reduce_kernel   <<<NPART, 256, 0, stream>>>(partials, bpart, cnt, (float*)d_out);
}

// Round 3
// 35.194 us; speedup vs baseline: 1.2458x; 1.0358x over previous
//
#include <hip/hip_runtime.h>

typedef float f4 __attribute__((ext_vector_type(4)));
typedef float f2 __attribute__((ext_vector_type(2)));

#define PAD 68              // LDS row pitch (floats); even (8B-aligned), 68%32=4 spreads banks
#define NPART 256           // gram blocks = partial count
#define PART_STRIDE 12288   // 3 * 64*64 floats per block partial

// ws layout (floats):
// [0, 3145728)      partials [256][3][4096]
// [3145728, +256)   per-block v partials (K2)
// [3145984]         uint counter

__global__ __launch_bounds__(1024) void fused_gram_kernel(
    const float* __restrict__ p1, const float* __restrict__ p2,
    float* __restrict__ partials, unsigned* __restrict__ cnt)
{
    __shared__ float la[32 * PAD];
    __shared__ float lb[32 * PAD];
    __shared__ float nred[64][17];   // [input*32+row][4-ch chunk]
    __shared__ float sa[32], sb[32];
    const int t  = threadIdx.x;
    const int b  = blockIdx.x >> 5;   // batch 0..7
    const int oi = blockIdx.x & 31;   // pooled row strip 0..31

    if (blockIdx.x == 0 && t == 0) *cnt = 0u;   // reset K2's ticket each call

    // ---- pool 4x4 means: 64 ch x 32 oj per input, into LDS [oj][c]
    #pragma unroll
    for (int k = 0; k < 2; ++k) {
        const int idx = k * 1024 + t;     // 0..2047
        const int c   = idx >> 5;
        const int oj  = idx & 31;
        const long off = (long)((b * 64 + c) * 128 + oi * 4) * 128 + oj * 4;
        const float* s1 = p1 + off;
        const float* s2 = p2 + off;
        f4 va = *(const f4*)(s1) + *(const f4*)(s1 + 128)
              + *(const f4*)(s1 + 256) + *(const f4*)(s1 + 384);
        f4 vb = *(const f4*)(s2) + *(const f4*)(s2 + 128)
              + *(const f4*)(s2 + 256) + *(const f4*)(s2 + 384);
        la[oj * PAD + c] = ((va[0] + va[1]) + (va[2] + va[3])) * 0.0625f;
        lb[oj * PAD + c] = ((vb[0] + vb[1]) + (vb[2] + vb[3])) * 0.0625f;
    }
    __syncthreads();

    // ---- row L2 norms over 64 ch: 32 rows x 2 inputs x 16 chunks of 4 ch
    {
        const int r = t & 31, g = t >> 5;        // g = 0..31
        const int m = g >> 4, q = g & 15;        // input, chunk
        const float* src = m ? lb : la;
        float ss = 0.f;
        #pragma unroll
        for (int j = 0; j < 4; ++j) {
            const float v = src[r * PAD + q * 4 + j];
            ss = fmaf(v, v, ss);
        }
        nred[m * 32 + r][q] = ss;
    }
    __syncthreads();
    if (t < 64) {
        const int m = t >> 5, r = t & 31;
        float ss = 0.f;
        #pragma unroll
        for (int q = 0; q < 16; ++q) ss += nred[m * 32 + r][q];
        const float rs = 1.0f / fmaxf(sqrtf(ss), 1e-8f);
        if (m) sb[r] = rs; else sa[r] = rs;
    }
    __syncthreads();

    // ---- scale rows in place
    #pragma unroll
    for (int k = 0; k < 2; ++k) {
        const int idx = k * 1024 + t;
        const int c = idx >> 5, oj = idx & 31;
        la[oj * PAD + c] *= sa[oj];
        lb[oj * PAD + c] *= sb[oj];
    }
    __syncthreads();

    // ---- three 64x64 channel Grams over this block's 32 rows.
    // thread owns a 2x2 tile (rows c1..c1+1, cols c2..c2+1) of each Gram.
    const int c1 = (t >> 5) * 2;      // broadcast within half-wave
    const int c2 = (t & 31) * 2;      // stride-2 across lanes (2-way = free)
    f2 aa0 = {}, aa1 = {}, ab0 = {}, ab1 = {}, bb0 = {}, bb1 = {};

    #pragma unroll 8
    for (int r = 0; r < 32; ++r) {
        const f2 a1 = *(const f2*)&la[r * PAD + c1];
        const f2 a2 = *(const f2*)&la[r * PAD + c2];
        const f2 b1 = *(const f2*)&lb[r * PAD + c1];
        const f2 b2 = *(const f2*)&lb[r * PAD + c2];
        aa0 += a2 * a1[0];  aa1 += a2 * a1[1];
        ab0 += b2 * a1[0];  ab1 += b2 * a1[1];
        bb0 += b2 * b1[0];  bb1 += b2 * b1[1];
    }

    float* P = partials + (long)blockIdx.x * PART_STRIDE;
    *(f2*)&P[0 * 4096 + (c1    ) * 64 + c2] = aa0;
    *(f2*)&P[0 * 4096 + (c1 + 1) * 64 + c2] = aa1;
    *(f2*)&P[1 * 4096 + (c1    ) * 64 + c2] = ab0;
    *(f2*)&P[1 * 4096 + (c1 + 1) * 64 + c2] = ab1;
    *(f2*)&P[2 * 4096 + (c1    ) * 64 + c2] = bb0;
    *(f2*)&P[2 * 4096 + (c1 + 1) * 64 + c2] = bb1;
}

// 256 blocks x 16 gram entries: sum partials over the 256 blocks, form
// v = saa^2 - 2 sab^2 + sbb^2 per entry, block-reduce, last block finishes.
__global__ __launch_bounds__(256) void reduce_kernel(
    const float* __restrict__ partials, float* __restrict__ bpart,
    unsigned* __restrict__ cnt, float* __restrict__ out)
{
    __shared__ float red[3][16][17];
    __shared__ float vred[16];
    __shared__ float fr[256];
    __shared__ unsigned last_flag;
    const int t  = threadIdx.x;
    const int el = t & 15;       // entry within block
    const int pc = t >> 4;       // partial chunk 0..15 (16 partials each)
    const int e  = blockIdx.x * 16 + el;

    float saa = 0.f, sab = 0.f, sbb = 0.f;
    #pragma unroll 4
    for (int i = 0; i < 16; ++i) {
        const float* P = partials + (long)(pc * 16 + i) * PART_STRIDE;
        saa += P[e];
        sab += P[4096 + e];
        sbb += P[8192 + e];
    }
    red[0][el][pc] = saa; red[1][el][pc] = sab; red[2][el][pc] = sbb;
    __syncthreads();

    if (t < 16) {
        float a = 0.f, m = 0.f, bv = 0.f;
        #pragma unroll
        for (int p = 0; p < 16; ++p) {
            a  += red[0][t][p];
            m  += red[1][t][p];
            bv += red[2][t][p];
        }
        vred[t] = fmaf(a, a, fmaf(bv, bv, -2.0f * (m * m)));
    }
    __syncthreads();

    if (t == 0) {
        float s = 0.f;
        #pragma unroll
        for (int i = 0; i < 16; ++i) s += vred[i];
        __hip_atomic_store(&bpart[blockIdx.x], s, __ATOMIC_RELEASE,
                           __HIP_MEMORY_SCOPE_AGENT);
        unsigned old = __hip_atomic_fetch_add(cnt, 1u, __ATOMIC_ACQ_REL,
                                              __HIP_MEMORY_SCOPE_AGENT);
        last_flag = (old == NPART - 1) ? 1u : 0u;
    }
    __syncthreads();

    if (last_flag) {   // block-uniform
        fr[t] = __hip_atomic_load(&bpart[t], __ATOMIC_ACQUIRE,
                                  __HIP_MEMORY_SCOPE_AGENT);
        __syncthreads();
        for (int s2 = 128; s2 > 0; s2 >>= 1) {
            if (t < s2) fr[t] += fr[t + s2];
            __syncthreads();
        }
        if (t == 0) out[0] = fr[0] * (1.0f / 67108864.0f);  // / 8192^2
    }
}

extern "C" void kernel_launch(void* const* d_in, const int* in_sizes, int n_in,
                              void* d_out, int out_size, void* d_ws, size_t ws_size,
                              hipStream_t stream)
{
    const float* p1 = (const float*)d_in[0];
    const float* p2 = (const float*)d_in[1];
    float* ws       = (float*)d_ws;
    float* partials = ws;                                  // 256*12288
    float* bpart    = ws + (long)NPART * PART_STRIDE;      // 256
    unsigned* cnt   = (unsigned*)(bpart + NPART);          // 1

    fused_gram_kernel<<<NPART, 1024, 0, stream>>>(p1, p2, partials, cnt);
    reduce_kernel   <<<NPART, 256, 0, stream>>>(partials, bpart, cnt, (float*)d_out);
}